// Round 5
// baseline (207.822 us; speedup 1.0000x reference)
//
#include <hip/hip_runtime.h>

// Problem constants (B=16, T=2048, D=512, A=128)
#define NB 16
#define NT 2048
#define ND 512
#define NA 128
#define EPSV 1e-6f
#define SCALE 0.08838834764831845f  // 128^-0.5
#define NCH 4        // s-chunks in attention
#define SCH 512      // s-chunk length

typedef __bf16 bf16;
typedef __bf16 bf16x4 __attribute__((ext_vector_type(4)));
typedef __bf16 bf16x8 __attribute__((ext_vector_type(8)));
typedef float f32x4 __attribute__((ext_vector_type(4)));

// ---------------------------------------------------------------------------
// Kernel 0: build W^T bf16 [256][512]  (rows 0..127 = Wq cols, 128..255 = Wk)
// ---------------------------------------------------------------------------
__global__ void prep_wt(const float* __restrict__ Wq, const float* __restrict__ Wk,
                        bf16* __restrict__ WT) {
    int n = blockIdx.x;
    const float* W = (n < NA) ? Wq : Wk;
    int col = n & (NA - 1);
    for (int k = threadIdx.x; k < ND; k += blockDim.x)
        WT[(size_t)n * ND + k] = (bf16)W[(size_t)k * NA + col];
}

// ---------------------------------------------------------------------------
// Kernel 1: fused norm + V + QK projection GEMM. 16 rows/block, grid 2048.
// ---------------------------------------------------------------------------
__launch_bounds__(256)
__global__ void norm_proj(const float* __restrict__ x, const float* __restrict__ Wv,
                          const float* __restrict__ bvp, const bf16* __restrict__ WT,
                          const float* __restrict__ bq, const float* __restrict__ bk,
                          bf16* __restrict__ QK, float* __restrict__ Vout) {
    __shared__ bf16 xn[16 * ND];  // 16 KB, XOR-swizzled rows
    const int tid = threadIdx.x;
    const int lane = tid & 63, wv = tid >> 6;
    const int row0 = blockIdx.x * 16;

    float wvv[8];
    float sumw = 0.f;
#pragma unroll
    for (int i = 0; i < 4; ++i) { wvv[i]     = Wv[lane * 4 + i];       sumw += wvv[i]; }
#pragma unroll
    for (int i = 0; i < 4; ++i) { wvv[4 + i] = Wv[256 + lane * 4 + i]; sumw += wvv[4 + i]; }
#pragma unroll
    for (int m = 1; m < 64; m <<= 1) sumw += __shfl_xor(sumw, m);
    const float bvs = bvp[0];

#pragma unroll
    for (int r = 0; r < 4; ++r) {
        const int lrow = wv * 4 + r;
        const int grow = row0 + lrow;
        const float* xr = x + (size_t)grow * ND;
        f32x4 a = *(const f32x4*)(xr + lane * 4);
        f32x4 b = *(const f32x4*)(xr + 256 + lane * 4);
        float s = 0.f, sq = 0.f, dw = 0.f;
#pragma unroll
        for (int i = 0; i < 4; ++i) { s += a[i]; sq += a[i] * a[i]; dw += a[i] * wvv[i]; }
#pragma unroll
        for (int i = 0; i < 4; ++i) { s += b[i]; sq += b[i] * b[i]; dw += b[i] * wvv[4 + i]; }
#pragma unroll
        for (int m = 1; m < 64; m <<= 1) {
            s  += __shfl_xor(s, m);
            sq += __shfl_xor(sq, m);
            dw += __shfl_xor(dw, m);
        }
        const float mu  = s * (1.f / 512.f);
        float var = (sq - 512.f * mu * mu) * (1.f / 511.f);
        var = fmaxf(var, 0.f);
        const float inv = 1.f / (sqrtf(var) + EPSV);
        if (lane == 0) Vout[grow] = (dw - mu * sumw) * inv + bvs;

        const int sw = (lrow & 7) << 4;
        bf16x4 v0, v1;
#pragma unroll
        for (int i = 0; i < 4; ++i) v0[i] = (bf16)((a[i] - mu) * inv);
#pragma unroll
        for (int i = 0; i < 4; ++i) v1[i] = (bf16)((b[i] - mu) * inv);
        *(bf16x4*)((char*)xn + lrow * 1024 + ((lane * 8) ^ sw))       = v0;
        *(bf16x4*)((char*)xn + lrow * 1024 + ((512 + lane * 8) ^ sw)) = v1;
    }
    __syncthreads();

    const int c = lane & 15, g = lane >> 4;
    const int asw = (c & 7) << 4;
    f32x4 acc[4];
#pragma unroll
    for (int i = 0; i < 4; ++i) acc[i] = f32x4{0.f, 0.f, 0.f, 0.f};

    for (int ks = 0; ks < 16; ++ks) {
        const bf16x8 af = *(const bf16x8*)((const char*)xn + c * 1024 +
                                           ((ks * 64 + g * 16) ^ asw));
#pragma unroll
        for (int i = 0; i < 4; ++i) {
            const int n = wv * 64 + i * 16 + c;
            const bf16x8 bfr = *(const bf16x8*)(WT + (size_t)n * ND + ks * 32 + g * 8);
            acc[i] = __builtin_amdgcn_mfma_f32_16x16x32_bf16(af, bfr, acc[i], 0, 0, 0);
        }
    }
#pragma unroll
    for (int i = 0; i < 4; ++i) {
        const int n = wv * 64 + i * 16 + c;
        const float bias = (n < NA) ? bq[n] : bk[n - NA];
#pragma unroll
        for (int j = 0; j < 4; ++j)
            QK[(size_t)(row0 + g * 4 + j) * 256 + n] = (bf16)(acc[i][j] + bias);
    }
}

// ---------------------------------------------------------------------------
// Kernel 2: pass1 — per-chunk sums l = sum(exp s), w = sum(exp s * V).
// Waves split the s-dim: no LDS K tile, no barriers, K frags direct from L2.
// Q (B-op) for all 64 t-rows held in registers.
// ---------------------------------------------------------------------------
__launch_bounds__(256, 3)
__global__ void attn_pass1(const bf16* __restrict__ QK, const float* __restrict__ Vg,
                           float* __restrict__ pl, float* __restrict__ pw) {
    __shared__ float redl[4][64], redw[4][64];
    const int tid = threadIdx.x;
    const int lane = tid & 63, w = tid >> 6;
    const int b = blockIdx.z, t0 = blockIdx.x * 64, sc = blockIdx.y;
    const int c = lane & 15, g = lane >> 4;

    // Q B-fragments: 4 t-blocks x 4 k-slices (col = c, k = ks*32 + g*8)
    bf16x8 qf[4][4];
#pragma unroll
    for (int tb = 0; tb < 4; ++tb) {
        const bf16* qrow = QK + (size_t)(b * NT + t0 + tb * 16 + c) * 256;
#pragma unroll
        for (int ks = 0; ks < 4; ++ks)
            qf[tb][ks] = *(const bf16x8*)(qrow + ks * 32 + g * 8);
    }

    // K A-fragments: this wave's s-rows = sc*SCH + tt*64 + w*16 + c
    const bf16* kp = QK + (size_t)(b * NT + sc * SCH + w * 16 + c) * 256 + NA + g * 8;
    const float* vp = Vg + b * NT + sc * SCH + w * 16 + g * 4;

    bf16x8 kf[4], kfn[4];
#pragma unroll
    for (int ks = 0; ks < 4; ++ks) kf[ks] = *(const bf16x8*)(kp + ks * 32);

    float l_loc[4] = {0.f, 0.f, 0.f, 0.f}, w_loc[4] = {0.f, 0.f, 0.f, 0.f};

    for (int tt = 0; tt < SCH / 64; ++tt) {
        if (tt + 1 < SCH / 64) {
#pragma unroll
            for (int ks = 0; ks < 4; ++ks)
                kfn[ks] = *(const bf16x8*)(kp + (size_t)(tt + 1) * 64 * 256 + ks * 32);
        }
        const f32x4 vv = *(const f32x4*)(vp + tt * 64);
        f32x4 acc[4];
#pragma unroll
        for (int tb = 0; tb < 4; ++tb) acc[tb] = f32x4{0.f, 0.f, 0.f, 0.f};
#pragma unroll
        for (int tb = 0; tb < 4; ++tb)
#pragma unroll
            for (int ks = 0; ks < 4; ++ks)
                acc[tb] = __builtin_amdgcn_mfma_f32_16x16x32_bf16(kf[ks], qf[tb][ks],
                                                                  acc[tb], 0, 0, 0);
#pragma unroll
        for (int tb = 0; tb < 4; ++tb)
#pragma unroll
            for (int jj = 0; jj < 4; ++jj) {
                const float p = __expf(acc[tb][jj] * SCALE);
                l_loc[tb] += p;
                w_loc[tb] += p * vv[jj];
            }
#pragma unroll
        for (int ks = 0; ks < 4; ++ks) kf[ks] = kfn[ks];
    }

    // reduce over g (xor 16/32 keeps c, tb fixed)
#pragma unroll
    for (int tb = 0; tb < 4; ++tb) {
#pragma unroll
        for (int mask = 16; mask <= 32; mask <<= 1) {
            l_loc[tb] += __shfl_xor(l_loc[tb], mask);
            w_loc[tb] += __shfl_xor(w_loc[tb], mask);
        }
    }
    if (g == 0) {
#pragma unroll
        for (int tb = 0; tb < 4; ++tb) {
            redl[w][tb * 16 + c] = l_loc[tb];
            redw[w][tb * 16 + c] = w_loc[tb];
        }
    }
    __syncthreads();
    if (tid < 64) {
        float L = 0.f, W = 0.f;
#pragma unroll
        for (int ww = 0; ww < 4; ++ww) { L += redl[ww][tid]; W += redw[ww][tid]; }
        const int idx = sc * (NB * NT) + b * NT + t0 + tid;
        pl[idx] = L;
        pw[idx] = W;
    }
}

// ---------------------------------------------------------------------------
// Kernel 3: merge the 4 chunk-partials -> 1/l, out_w
// ---------------------------------------------------------------------------
__global__ void attn_reduce(const float* __restrict__ pl, const float* __restrict__ pw,
                            float* __restrict__ linv, float* __restrict__ out_w) {
    const int r = blockIdx.x * 256 + threadIdx.x;  // 0 .. NB*NT-1
    float L = 0.f, W = 0.f;
#pragma unroll
    for (int ch = 0; ch < NCH; ++ch) {
        L += pl[ch * (NB * NT) + r];
        W += pw[ch * (NB * NT) + r];
    }
    linv[r] = 1.f / L;
    out_w[r] = W / L;
}

// ---------------------------------------------------------------------------
// Kernel 4: pass2 — recompute scores, write normalized w_att.
// Same barrier-free s-split structure; f32x4 coalesced-ish stores.
// ---------------------------------------------------------------------------
__launch_bounds__(256, 3)
__global__ void attn_pass2(const bf16* __restrict__ QK, const float* __restrict__ linv,
                           float* __restrict__ out_att) {
    const int tid = threadIdx.x;
    const int lane = tid & 63, w = tid >> 6;
    const int b = blockIdx.z, t0 = blockIdx.x * 64, sc = blockIdx.y;
    const int c = lane & 15, g = lane >> 4;

    bf16x8 qf[4][4];
    float li[4];
#pragma unroll
    for (int tb = 0; tb < 4; ++tb) {
        const bf16* qrow = QK + (size_t)(b * NT + t0 + tb * 16 + c) * 256;
#pragma unroll
        for (int ks = 0; ks < 4; ++ks)
            qf[tb][ks] = *(const bf16x8*)(qrow + ks * 32 + g * 8);
        li[tb] = linv[b * NT + t0 + tb * 16 + c];
    }

    const bf16* kp = QK + (size_t)(b * NT + sc * SCH + w * 16 + c) * 256 + NA + g * 8;

    bf16x8 kf[4], kfn[4];
#pragma unroll
    for (int ks = 0; ks < 4; ++ks) kf[ks] = *(const bf16x8*)(kp + ks * 32);

    // store bases: row t = t0 + tb*16 + c, col base = sc*SCH + w*16 + g*4
    float* obase = out_att + (size_t)(b * NT) * NT + sc * SCH + w * 16 + g * 4;

    for (int tt = 0; tt < SCH / 64; ++tt) {
        if (tt + 1 < SCH / 64) {
#pragma unroll
            for (int ks = 0; ks < 4; ++ks)
                kfn[ks] = *(const bf16x8*)(kp + (size_t)(tt + 1) * 64 * 256 + ks * 32);
        }
        f32x4 acc[4];
#pragma unroll
        for (int tb = 0; tb < 4; ++tb) acc[tb] = f32x4{0.f, 0.f, 0.f, 0.f};
#pragma unroll
        for (int tb = 0; tb < 4; ++tb)
#pragma unroll
            for (int ks = 0; ks < 4; ++ks)
                acc[tb] = __builtin_amdgcn_mfma_f32_16x16x32_bf16(kf[ks], qf[tb][ks],
                                                                  acc[tb], 0, 0, 0);
#pragma unroll
        for (int tb = 0; tb < 4; ++tb) {
            f32x4 wv4;
#pragma unroll
            for (int jj = 0; jj < 4; ++jj)
                wv4[jj] = __expf(acc[tb][jj] * SCALE) * li[tb];
            *(f32x4*)(obase + (size_t)(t0 + tb * 16 + c) * NT + tt * 64) = wv4;
        }
#pragma unroll
        for (int ks = 0; ks < 4; ++ks) kf[ks] = kfn[ks];
    }
}

// ---------------------------------------------------------------------------
extern "C" void kernel_launch(void* const* d_in, const int* in_sizes, int n_in,
                              void* d_out, int out_size, void* d_ws, size_t ws_size,
                              hipStream_t stream) {
    const float* x  = (const float*)d_in[0];
    const float* Wq = (const float*)d_in[1];
    const float* bq = (const float*)d_in[2];
    const float* Wk = (const float*)d_in[3];
    const float* bk = (const float*)d_in[4];
    const float* Wv = (const float*)d_in[5];
    const float* bv = (const float*)d_in[6];

    float* out_w   = (float*)d_out;            // [B,T,1] = 32768
    float* out_att = (float*)d_out + NB * NT;  // [B,T,T]

    char* ws = (char*)d_ws;
    bf16*  WT   = (bf16*)ws;                         // 262144 B
    float* V    = (float*)(ws + 262144);             // 131072 B
    bf16*  QK   = (bf16*)(ws + 393216);              // 16 MB
    float* pl   = (float*)(ws + 17170432);           // 512 KB
    float* pw   = (float*)(ws + 17694720);           // 512 KB
    float* linv = (float*)(ws + 18219008);           // 128 KB

    prep_wt<<<dim3(256), dim3(256), 0, stream>>>(Wq, Wk, WT);
    norm_proj<<<dim3((NB * NT) / 16), dim3(256), 0, stream>>>(x, Wv, bv, WT, bq, bk, QK, V);
    attn_pass1<<<dim3(NT / 64, NCH, NB), dim3(256), 0, stream>>>(QK, V, pl, pw);
    attn_reduce<<<dim3((NB * NT) / 256), dim3(256), 0, stream>>>(pl, pw, linv, out_w);
    attn_pass2<<<dim3(NT / 64, NCH, NB), dim3(256), 0, stream>>>(QK, linv, out_att);
}

// Round 6
// 191.533 us; speedup vs baseline: 1.0850x; 1.0850x over previous
//
#include <hip/hip_runtime.h>

// Problem constants (B=16, T=2048, D=512, A=128)
#define NB 16
#define NT 2048
#define ND 512
#define NA 128
#define EPSV 1e-6f
#define SCALE 0.08838834764831845f  // 128^-0.5
#define NCH 4        // s-chunks in attention
#define SCH 512      // s-chunk length

typedef __bf16 bf16;
typedef __bf16 bf16x4 __attribute__((ext_vector_type(4)));
typedef __bf16 bf16x8 __attribute__((ext_vector_type(8)));
typedef float f32x4 __attribute__((ext_vector_type(4)));

// ---------------------------------------------------------------------------
// Kernel 0: build W^T bf16 [256][512]  (rows 0..127 = Wq cols, 128..255 = Wk)
// ---------------------------------------------------------------------------
__global__ void prep_wt(const float* __restrict__ Wq, const float* __restrict__ Wk,
                        bf16* __restrict__ WT) {
    int n = blockIdx.x;
    const float* W = (n < NA) ? Wq : Wk;
    int col = n & (NA - 1);
    for (int k = threadIdx.x; k < ND; k += blockDim.x)
        WT[(size_t)n * ND + k] = (bf16)W[(size_t)k * NA + col];
}

// ---------------------------------------------------------------------------
// Kernel 1: fused norm + V + QK projection GEMM. 16 rows/block, grid 2048.
// ---------------------------------------------------------------------------
__launch_bounds__(256)
__global__ void norm_proj(const float* __restrict__ x, const float* __restrict__ Wv,
                          const float* __restrict__ bvp, const bf16* __restrict__ WT,
                          const float* __restrict__ bq, const float* __restrict__ bk,
                          bf16* __restrict__ QK, float* __restrict__ Vout) {
    __shared__ bf16 xn[16 * ND];  // 16 KB, XOR-swizzled rows
    const int tid = threadIdx.x;
    const int lane = tid & 63, wv = tid >> 6;
    const int row0 = blockIdx.x * 16;

    float wvv[8];
    float sumw = 0.f;
#pragma unroll
    for (int i = 0; i < 4; ++i) { wvv[i]     = Wv[lane * 4 + i];       sumw += wvv[i]; }
#pragma unroll
    for (int i = 0; i < 4; ++i) { wvv[4 + i] = Wv[256 + lane * 4 + i]; sumw += wvv[4 + i]; }
#pragma unroll
    for (int m = 1; m < 64; m <<= 1) sumw += __shfl_xor(sumw, m);
    const float bvs = bvp[0];

#pragma unroll
    for (int r = 0; r < 4; ++r) {
        const int lrow = wv * 4 + r;
        const int grow = row0 + lrow;
        const float* xr = x + (size_t)grow * ND;
        f32x4 a = *(const f32x4*)(xr + lane * 4);
        f32x4 b = *(const f32x4*)(xr + 256 + lane * 4);
        float s = 0.f, sq = 0.f, dw = 0.f;
#pragma unroll
        for (int i = 0; i < 4; ++i) { s += a[i]; sq += a[i] * a[i]; dw += a[i] * wvv[i]; }
#pragma unroll
        for (int i = 0; i < 4; ++i) { s += b[i]; sq += b[i] * b[i]; dw += b[i] * wvv[4 + i]; }
#pragma unroll
        for (int m = 1; m < 64; m <<= 1) {
            s  += __shfl_xor(s, m);
            sq += __shfl_xor(sq, m);
            dw += __shfl_xor(dw, m);
        }
        const float mu  = s * (1.f / 512.f);
        float var = (sq - 512.f * mu * mu) * (1.f / 511.f);
        var = fmaxf(var, 0.f);
        const float inv = 1.f / (sqrtf(var) + EPSV);
        if (lane == 0) Vout[grow] = (dw - mu * sumw) * inv + bvs;

        const int sw = (lrow & 7) << 4;
        bf16x4 v0, v1;
#pragma unroll
        for (int i = 0; i < 4; ++i) v0[i] = (bf16)((a[i] - mu) * inv);
#pragma unroll
        for (int i = 0; i < 4; ++i) v1[i] = (bf16)((b[i] - mu) * inv);
        *(bf16x4*)((char*)xn + lrow * 1024 + ((lane * 8) ^ sw))       = v0;
        *(bf16x4*)((char*)xn + lrow * 1024 + ((512 + lane * 8) ^ sw)) = v1;
    }
    __syncthreads();

    const int c = lane & 15, g = lane >> 4;
    const int asw = (c & 7) << 4;
    f32x4 acc[4];
#pragma unroll
    for (int i = 0; i < 4; ++i) acc[i] = f32x4{0.f, 0.f, 0.f, 0.f};

    for (int ks = 0; ks < 16; ++ks) {
        const bf16x8 af = *(const bf16x8*)((const char*)xn + c * 1024 +
                                           ((ks * 64 + g * 16) ^ asw));
#pragma unroll
        for (int i = 0; i < 4; ++i) {
            const int n = wv * 64 + i * 16 + c;
            const bf16x8 bfr = *(const bf16x8*)(WT + (size_t)n * ND + ks * 32 + g * 8);
            acc[i] = __builtin_amdgcn_mfma_f32_16x16x32_bf16(af, bfr, acc[i], 0, 0, 0);
        }
    }
#pragma unroll
    for (int i = 0; i < 4; ++i) {
        const int n = wv * 64 + i * 16 + c;
        const float bias = (n < NA) ? bq[n] : bk[n - NA];
#pragma unroll
        for (int j = 0; j < 4; ++j)
            QK[(size_t)(row0 + g * 4 + j) * 256 + n] = (bf16)(acc[i][j] + bias);
    }
}

// ---------------------------------------------------------------------------
// Kernel 2: pass1 — per-chunk sums l = sum(exp s), w = sum(exp s * V).
// Double-buffered LDS K tile (1 barrier/tile); waves split s within the tile
// (4 ds_read_b128/wave/tile); Q B-frags for all 64 t-rows in registers.
// ---------------------------------------------------------------------------
__launch_bounds__(256)
__global__ void attn_pass1(const bf16* __restrict__ QK, const float* __restrict__ Vg,
                           float* __restrict__ pl, float* __restrict__ pw) {
    __shared__ bf16 Kt[2][64 * NA];     // 2 x 16 KB, XOR-swizzled
    __shared__ float redl[4][64], redw[4][64];
    const int tid = threadIdx.x;
    const int lane = tid & 63, w = tid >> 6;
    const int b = blockIdx.z, t0 = blockIdx.x * 64, sc = blockIdx.y;
    const int c = lane & 15, g = lane >> 4;

    // Q B-fragments: 4 t-blocks x 4 k-slices (col = c, k = ks*32 + g*8)
    bf16x8 qf[4][4];
#pragma unroll
    for (int tb = 0; tb < 4; ++tb) {
        const bf16* qrow = QK + (size_t)(b * NT + t0 + tb * 16 + c) * 256;
#pragma unroll
        for (int ks = 0; ks < 4; ++ks)
            qf[tb][ks] = *(const bf16x8*)(qrow + ks * 32 + g * 8);
    }

    // staging map: thread stages rows srow + i*16 (i=0..3), 16B at col scc
    const int srow = tid >> 4, scc = tid & 15;
    const bf16* kbase = QK + (size_t)(b * NT + sc * SCH + srow) * 256 + NA + scc * 8;
    const int koff = srow * 256 + ((scc * 16) ^ ((srow & 7) << 4));
    bf16x8 sreg[4];

    // prologue: stage tile 0 into buf 0
#pragma unroll
    for (int i = 0; i < 4; ++i)
        sreg[i] = *(const bf16x8*)(kbase + (size_t)(i * 16) * 256);
#pragma unroll
    for (int i = 0; i < 4; ++i)
        *(bf16x8*)((char*)Kt[0] + koff + i * 4096) = sreg[i];
    __syncthreads();

    const float* vp = Vg + b * NT + sc * SCH + w * 16 + g * 4;
    const int asw = (c & 7) << 4;
    float l_loc[4] = {0.f, 0.f, 0.f, 0.f}, w_loc[4] = {0.f, 0.f, 0.f, 0.f};

    for (int tt = 0; tt < SCH / 64; ++tt) {
        if (tt + 1 < SCH / 64) {
#pragma unroll
            for (int i = 0; i < 4; ++i)
                sreg[i] = *(const bf16x8*)(kbase + (size_t)((tt + 1) * 64 + i * 16) * 256);
        }
        // this wave's A-frags: tile rows w*16 + c
        const char* ab = (const char*)Kt[tt & 1] + (w * 16 + c) * 256;
        bf16x8 af[4];
#pragma unroll
        for (int ks = 0; ks < 4; ++ks)
            af[ks] = *(const bf16x8*)(ab + ((ks * 64 + g * 16) ^ asw));

        f32x4 acc[4];
#pragma unroll
        for (int tb = 0; tb < 4; ++tb) acc[tb] = f32x4{0.f, 0.f, 0.f, 0.f};
#pragma unroll
        for (int tb = 0; tb < 4; ++tb)
#pragma unroll
            for (int ks = 0; ks < 4; ++ks)
                acc[tb] = __builtin_amdgcn_mfma_f32_16x16x32_bf16(af[ks], qf[tb][ks],
                                                                  acc[tb], 0, 0, 0);
        const f32x4 vv = *(const f32x4*)(vp + tt * 64);
#pragma unroll
        for (int tb = 0; tb < 4; ++tb)
#pragma unroll
            for (int jj = 0; jj < 4; ++jj) {
                const float p = __expf(acc[tb][jj] * SCALE);
                l_loc[tb] += p;
                w_loc[tb] += p * vv[jj];
            }
        if (tt + 1 < SCH / 64) {
#pragma unroll
            for (int i = 0; i < 4; ++i)
                *(bf16x8*)((char*)Kt[(tt + 1) & 1] + koff + i * 4096) = sreg[i];
        }
        __syncthreads();
    }

    // reduce over g (xor 16/32 keeps c, tb fixed), then across waves (s-split)
#pragma unroll
    for (int tb = 0; tb < 4; ++tb) {
#pragma unroll
        for (int mask = 16; mask <= 32; mask <<= 1) {
            l_loc[tb] += __shfl_xor(l_loc[tb], mask);
            w_loc[tb] += __shfl_xor(w_loc[tb], mask);
        }
    }
    if (g == 0) {
#pragma unroll
        for (int tb = 0; tb < 4; ++tb) {
            redl[w][tb * 16 + c] = l_loc[tb];
            redw[w][tb * 16 + c] = w_loc[tb];
        }
    }
    __syncthreads();
    if (tid < 64) {
        float L = 0.f, W = 0.f;
#pragma unroll
        for (int ww = 0; ww < 4; ++ww) { L += redl[ww][tid]; W += redw[ww][tid]; }
        const int idx = sc * (NB * NT) + b * NT + t0 + tid;
        pl[idx] = L;
        pw[idx] = W;
    }
}

// ---------------------------------------------------------------------------
// Kernel 3: merge the 4 chunk-partials -> 1/l, out_w
// ---------------------------------------------------------------------------
__global__ void attn_reduce(const float* __restrict__ pl, const float* __restrict__ pw,
                            float* __restrict__ linv, float* __restrict__ out_w) {
    const int r = blockIdx.x * 256 + threadIdx.x;  // 0 .. NB*NT-1
    float L = 0.f, W = 0.f;
#pragma unroll
    for (int ch = 0; ch < NCH; ++ch) {
        L += pl[ch * (NB * NT) + r];
        W += pw[ch * (NB * NT) + r];
    }
    linv[r] = 1.f / L;
    out_w[r] = W / L;
}

// ---------------------------------------------------------------------------
// Kernel 4: pass2 — recompute scores, write normalized w_att.
// Same double-buffered s-split structure; f32x4 stores.
// ---------------------------------------------------------------------------
__launch_bounds__(256)
__global__ void attn_pass2(const bf16* __restrict__ QK, const float* __restrict__ linv,
                           float* __restrict__ out_att) {
    __shared__ bf16 Kt[2][64 * NA];
    const int tid = threadIdx.x;
    const int lane = tid & 63, w = tid >> 6;
    const int b = blockIdx.z, t0 = blockIdx.x * 64, sc = blockIdx.y;
    const int c = lane & 15, g = lane >> 4;

    bf16x8 qf[4][4];
    float li[4];
#pragma unroll
    for (int tb = 0; tb < 4; ++tb) {
        const bf16* qrow = QK + (size_t)(b * NT + t0 + tb * 16 + c) * 256;
#pragma unroll
        for (int ks = 0; ks < 4; ++ks)
            qf[tb][ks] = *(const bf16x8*)(qrow + ks * 32 + g * 8);
        li[tb] = linv[b * NT + t0 + tb * 16 + c];
    }

    const int srow = tid >> 4, scc = tid & 15;
    const bf16* kbase = QK + (size_t)(b * NT + sc * SCH + srow) * 256 + NA + scc * 8;
    const int koff = srow * 256 + ((scc * 16) ^ ((srow & 7) << 4));
    bf16x8 sreg[4];

#pragma unroll
    for (int i = 0; i < 4; ++i)
        sreg[i] = *(const bf16x8*)(kbase + (size_t)(i * 16) * 256);
#pragma unroll
    for (int i = 0; i < 4; ++i)
        *(bf16x8*)((char*)Kt[0] + koff + i * 4096) = sreg[i];
    __syncthreads();

    const int asw = (c & 7) << 4;
    // store: row t = t0 + tb*16 + c, col = sc*SCH + tt*64 + w*16 + g*4
    float* obase = out_att + (size_t)(b * NT) * NT + sc * SCH + w * 16 + g * 4;

    for (int tt = 0; tt < SCH / 64; ++tt) {
        if (tt + 1 < SCH / 64) {
#pragma unroll
            for (int i = 0; i < 4; ++i)
                sreg[i] = *(const bf16x8*)(kbase + (size_t)((tt + 1) * 64 + i * 16) * 256);
        }
        const char* ab = (const char*)Kt[tt & 1] + (w * 16 + c) * 256;
        bf16x8 af[4];
#pragma unroll
        for (int ks = 0; ks < 4; ++ks)
            af[ks] = *(const bf16x8*)(ab + ((ks * 64 + g * 16) ^ asw));

        f32x4 acc[4];
#pragma unroll
        for (int tb = 0; tb < 4; ++tb) acc[tb] = f32x4{0.f, 0.f, 0.f, 0.f};
#pragma unroll
        for (int tb = 0; tb < 4; ++tb)
#pragma unroll
            for (int ks = 0; ks < 4; ++ks)
                acc[tb] = __builtin_amdgcn_mfma_f32_16x16x32_bf16(af[ks], qf[tb][ks],
                                                                  acc[tb], 0, 0, 0);
#pragma unroll
        for (int tb = 0; tb < 4; ++tb) {
            f32x4 wv4;
#pragma unroll
            for (int jj = 0; jj < 4; ++jj)
                wv4[jj] = __expf(acc[tb][jj] * SCALE) * li[tb];
            *(f32x4*)(obase + (size_t)(t0 + tb * 16 + c) * NT + tt * 64) = wv4;
        }
        if (tt + 1 < SCH / 64) {
#pragma unroll
            for (int i = 0; i < 4; ++i)
                *(bf16x8*)((char*)Kt[(tt + 1) & 1] + koff + i * 4096) = sreg[i];
        }
        __syncthreads();
    }
}

// ---------------------------------------------------------------------------
extern "C" void kernel_launch(void* const* d_in, const int* in_sizes, int n_in,
                              void* d_out, int out_size, void* d_ws, size_t ws_size,
                              hipStream_t stream) {
    const float* x  = (const float*)d_in[0];
    const float* Wq = (const float*)d_in[1];
    const float* bq = (const float*)d_in[2];
    const float* Wk = (const float*)d_in[3];
    const float* bk = (const float*)d_in[4];
    const float* Wv = (const float*)d_in[5];
    const float* bv = (const float*)d_in[6];

    float* out_w   = (float*)d_out;            // [B,T,1] = 32768
    float* out_att = (float*)d_out + NB * NT;  // [B,T,T]

    char* ws = (char*)d_ws;
    bf16*  WT   = (bf16*)ws;                         // 262144 B
    float* V    = (float*)(ws + 262144);             // 131072 B
    bf16*  QK   = (bf16*)(ws + 393216);              // 16 MB
    float* pl   = (float*)(ws + 17170432);           // 512 KB
    float* pw   = (float*)(ws + 17694720);           // 512 KB
    float* linv = (float*)(ws + 18219008);           // 128 KB

    prep_wt<<<dim3(256), dim3(256), 0, stream>>>(Wq, Wk, WT);
    norm_proj<<<dim3((NB * NT) / 16), dim3(256), 0, stream>>>(x, Wv, bv, WT, bq, bk, QK, V);
    attn_pass1<<<dim3(NT / 64, NCH, NB), dim3(256), 0, stream>>>(QK, V, pl, pw);
    attn_reduce<<<dim3((NB * NT) / 256), dim3(256), 0, stream>>>(pl, pw, linv, out_w);
    attn_pass2<<<dim3(NT / 64, NCH, NB), dim3(256), 0, stream>>>(QK, linv, out_att);
}

// Round 7
// 186.400 us; speedup vs baseline: 1.1149x; 1.0275x over previous
//
#include <hip/hip_runtime.h>

// Problem constants (B=16, T=2048, D=512, A=128)
#define NB 16
#define NT 2048
#define ND 512
#define NA 128
#define EPSV 1e-6f
#define SCALE 0.08838834764831845f  // 128^-0.5
#define NCH1 8       // s-chunks, pass1
#define SCH1 256
#define NCH2 4       // s-chunks, pass2
#define SCH2 512

typedef __bf16 bf16;
typedef __bf16 bf16x4 __attribute__((ext_vector_type(4)));
typedef __bf16 bf16x8 __attribute__((ext_vector_type(8)));
typedef float f32x4 __attribute__((ext_vector_type(4)));

// ---------------------------------------------------------------------------
// Kernel 0: build W^T bf16 [256][512]  (rows 0..127 = Wq cols, 128..255 = Wk)
// ---------------------------------------------------------------------------
__global__ void prep_wt(const float* __restrict__ Wq, const float* __restrict__ Wk,
                        bf16* __restrict__ WT) {
    int n = blockIdx.x;
    const float* W = (n < NA) ? Wq : Wk;
    int col = n & (NA - 1);
    for (int k = threadIdx.x; k < ND; k += blockDim.x)
        WT[(size_t)n * ND + k] = (bf16)W[(size_t)k * NA + col];
}

// ---------------------------------------------------------------------------
// Kernel 1: fused norm + V + QK projection GEMM. 16 rows/block, grid 2048.
// ---------------------------------------------------------------------------
__launch_bounds__(256)
__global__ void norm_proj(const float* __restrict__ x, const float* __restrict__ Wv,
                          const float* __restrict__ bvp, const bf16* __restrict__ WT,
                          const float* __restrict__ bq, const float* __restrict__ bk,
                          bf16* __restrict__ QK, float* __restrict__ Vout) {
    __shared__ bf16 xn[16 * ND];  // 16 KB, XOR-swizzled rows
    const int tid = threadIdx.x;
    const int lane = tid & 63, wv = tid >> 6;
    const int row0 = blockIdx.x * 16;

    float wvv[8];
    float sumw = 0.f;
#pragma unroll
    for (int i = 0; i < 4; ++i) { wvv[i]     = Wv[lane * 4 + i];       sumw += wvv[i]; }
#pragma unroll
    for (int i = 0; i < 4; ++i) { wvv[4 + i] = Wv[256 + lane * 4 + i]; sumw += wvv[4 + i]; }
#pragma unroll
    for (int m = 1; m < 64; m <<= 1) sumw += __shfl_xor(sumw, m);
    const float bvs = bvp[0];

#pragma unroll
    for (int r = 0; r < 4; ++r) {
        const int lrow = wv * 4 + r;
        const int grow = row0 + lrow;
        const float* xr = x + (size_t)grow * ND;
        f32x4 a = *(const f32x4*)(xr + lane * 4);
        f32x4 b = *(const f32x4*)(xr + 256 + lane * 4);
        float s = 0.f, sq = 0.f, dw = 0.f;
#pragma unroll
        for (int i = 0; i < 4; ++i) { s += a[i]; sq += a[i] * a[i]; dw += a[i] * wvv[i]; }
#pragma unroll
        for (int i = 0; i < 4; ++i) { s += b[i]; sq += b[i] * b[i]; dw += b[i] * wvv[4 + i]; }
#pragma unroll
        for (int m = 1; m < 64; m <<= 1) {
            s  += __shfl_xor(s, m);
            sq += __shfl_xor(sq, m);
            dw += __shfl_xor(dw, m);
        }
        const float mu  = s * (1.f / 512.f);
        float var = (sq - 512.f * mu * mu) * (1.f / 511.f);
        var = fmaxf(var, 0.f);
        const float inv = 1.f / (sqrtf(var) + EPSV);
        if (lane == 0) Vout[grow] = (dw - mu * sumw) * inv + bvs;

        const int sw = (lrow & 7) << 4;
        bf16x4 v0, v1;
#pragma unroll
        for (int i = 0; i < 4; ++i) v0[i] = (bf16)((a[i] - mu) * inv);
#pragma unroll
        for (int i = 0; i < 4; ++i) v1[i] = (bf16)((b[i] - mu) * inv);
        *(bf16x4*)((char*)xn + lrow * 1024 + ((lane * 8) ^ sw))       = v0;
        *(bf16x4*)((char*)xn + lrow * 1024 + ((512 + lane * 8) ^ sw)) = v1;
    }
    __syncthreads();

    const int c = lane & 15, g = lane >> 4;
    const int asw = (c & 7) << 4;
    f32x4 acc[4];
#pragma unroll
    for (int i = 0; i < 4; ++i) acc[i] = f32x4{0.f, 0.f, 0.f, 0.f};

    for (int ks = 0; ks < 16; ++ks) {
        const bf16x8 af = *(const bf16x8*)((const char*)xn + c * 1024 +
                                           ((ks * 64 + g * 16) ^ asw));
#pragma unroll
        for (int i = 0; i < 4; ++i) {
            const int n = wv * 64 + i * 16 + c;
            const bf16x8 bfr = *(const bf16x8*)(WT + (size_t)n * ND + ks * 32 + g * 8);
            acc[i] = __builtin_amdgcn_mfma_f32_16x16x32_bf16(af, bfr, acc[i], 0, 0, 0);
        }
    }
#pragma unroll
    for (int i = 0; i < 4; ++i) {
        const int n = wv * 64 + i * 16 + c;
        const float bias = (n < NA) ? bq[n] : bk[n - NA];
#pragma unroll
        for (int j = 0; j < 4; ++j)
            QK[(size_t)(row0 + g * 4 + j) * 256 + n] = (bf16)(acc[i][j] + bias);
    }
}

// ---------------------------------------------------------------------------
// Kernel 2: pass1 — per-chunk sums l = sum(exp s), w = sum(exp s * V).
// R4 structure (t-split waves, single LDS tile, reg-staged prefetch).
// Grid (sc, b, t): blocks sharing a K chunk land on the same XCD.
// ---------------------------------------------------------------------------
__launch_bounds__(256)
__global__ void attn_pass1(const bf16* __restrict__ QK, const float* __restrict__ Vg,
                           float* __restrict__ pl, float* __restrict__ pw) {
    __shared__ bf16 Kt[64 * NA];  // 16 KB, XOR-swizzled
    const int tid = threadIdx.x;
    const int lane = tid & 63, wv = tid >> 6;
    const int sc = blockIdx.x, b = blockIdx.y, t0 = blockIdx.z * 64;
    const int c = lane & 15, g = lane >> 4;
    const int trow = t0 + wv * 16 + c;

    bf16x8 qf[4];
    const bf16* qrow = QK + (size_t)(b * NT + trow) * 256;
#pragma unroll
    for (int ks = 0; ks < 4; ++ks) qf[ks] = *(const bf16x8*)(qrow + ks * 32 + g * 8);

    // staging map: thread stages rows srow + i*16 (i=0..3), 16B at col scc
    const int srow = tid >> 4, scc = tid & 15;
    const bf16* kbase = QK + (size_t)(b * NT + sc * SCH1 + srow) * 256 + NA + scc * 8;
    bf16* kdst = (bf16*)((char*)Kt + srow * 256 + ((scc * 16) ^ ((srow & 7) << 4)));
    bf16x8 sreg[4];

#pragma unroll
    for (int i = 0; i < 4; ++i)
        sreg[i] = *(const bf16x8*)(kbase + (size_t)(i * 16) * 256);

    const float* vbase = Vg + b * NT + sc * SCH1;
    float l_loc = 0.f, w_loc = 0.f;

    for (int tt = 0; tt < SCH1 / 64; ++tt) {
        __syncthreads();  // all waves done reading Kt (no-op first iter)
#pragma unroll
        for (int i = 0; i < 4; ++i)
            *(bf16x8*)((char*)kdst + i * 16 * 256) = sreg[i];
        if (tt + 1 < SCH1 / 64) {
#pragma unroll
            for (int i = 0; i < 4; ++i)
                sreg[i] = *(const bf16x8*)(kbase + (size_t)((tt + 1) * 64 + i * 16) * 256);
        }
        __syncthreads();  // Kt visible

#pragma unroll
        for (int ns = 0; ns < 4; ++ns) {
            f32x4 acc = f32x4{0.f, 0.f, 0.f, 0.f};
            const int rr = ns * 16 + c;
            const int rsw = (rr & 7) << 4;
#pragma unroll
            for (int ks = 0; ks < 4; ++ks) {
                const bf16x8 afr = *(const bf16x8*)((const char*)Kt + rr * 256 +
                                                    ((ks * 64 + g * 16) ^ rsw));
                acc = __builtin_amdgcn_mfma_f32_16x16x32_bf16(afr, qf[ks], acc, 0, 0, 0);
            }
            const f32x4 vv = *(const f32x4*)(vbase + tt * 64 + ns * 16 + g * 4);
#pragma unroll
            for (int jj = 0; jj < 4; ++jj) {
                const float p = __expf(acc[jj] * SCALE);
                l_loc += p;
                w_loc += p * vv[jj];
            }
        }
    }

    // merge partials across the 4 g-lanes sharing trow
#pragma unroll
    for (int mask = 16; mask <= 32; mask <<= 1) {
        l_loc += __shfl_xor(l_loc, mask);
        w_loc += __shfl_xor(w_loc, mask);
    }
    if (g == 0) {
        const int idx = sc * (NB * NT) + b * NT + trow;
        pl[idx] = l_loc;
        pw[idx] = w_loc;
    }
}

// ---------------------------------------------------------------------------
// Kernel 3: pass2 — sums the chunk partials itself (reduce folded in),
// recomputes scores, writes normalized w_att; sc==0 blocks write out_w.
// ---------------------------------------------------------------------------
__launch_bounds__(256)
__global__ void attn_pass2(const bf16* __restrict__ QK, const float* __restrict__ pl,
                           const float* __restrict__ pw, float* __restrict__ out_w,
                           float* __restrict__ out_att) {
    __shared__ bf16 Kt[64 * NA];
    const int tid = threadIdx.x;
    const int lane = tid & 63, wv = tid >> 6;
    const int sc = blockIdx.x, b = blockIdx.y, t0 = blockIdx.z * 64;
    const int c = lane & 15, g = lane >> 4;
    const int trow = t0 + wv * 16 + c;

    bf16x8 qf[4];
    const bf16* qrow = QK + (size_t)(b * NT + trow) * 256;
#pragma unroll
    for (int ks = 0; ks < 4; ++ks) qf[ks] = *(const bf16x8*)(qrow + ks * 32 + g * 8);

    // fold the chunk reduction: L, W for this lane's row
    float L = 0.f, W = 0.f;
#pragma unroll
    for (int ch = 0; ch < NCH1; ++ch) {
        L += pl[ch * (NB * NT) + b * NT + trow];
        W += pw[ch * (NB * NT) + b * NT + trow];
    }
    const float lrow = 1.f / L;
    if (sc == 0 && g == 0) out_w[b * NT + trow] = W * lrow;

    const int srow = tid >> 4, scc = tid & 15;
    const bf16* kbase = QK + (size_t)(b * NT + sc * SCH2 + srow) * 256 + NA + scc * 8;
    bf16* kdst = (bf16*)((char*)Kt + srow * 256 + ((scc * 16) ^ ((srow & 7) << 4)));
    bf16x8 sreg[4];

#pragma unroll
    for (int i = 0; i < 4; ++i)
        sreg[i] = *(const bf16x8*)(kbase + (size_t)(i * 16) * 256);

    float* orow = out_att + (size_t)(b * NT + trow) * NT;

    for (int tt = 0; tt < SCH2 / 64; ++tt) {
        __syncthreads();
#pragma unroll
        for (int i = 0; i < 4; ++i)
            *(bf16x8*)((char*)kdst + i * 16 * 256) = sreg[i];
        if (tt + 1 < SCH2 / 64) {
#pragma unroll
            for (int i = 0; i < 4; ++i)
                sreg[i] = *(const bf16x8*)(kbase + (size_t)((tt + 1) * 64 + i * 16) * 256);
        }
        __syncthreads();

        const int s0 = sc * SCH2 + tt * 64;
#pragma unroll
        for (int ns = 0; ns < 4; ++ns) {
            f32x4 acc = f32x4{0.f, 0.f, 0.f, 0.f};
            const int rr = ns * 16 + c;
            const int rsw = (rr & 7) << 4;
#pragma unroll
            for (int ks = 0; ks < 4; ++ks) {
                const bf16x8 afr = *(const bf16x8*)((const char*)Kt + rr * 256 +
                                                    ((ks * 64 + g * 16) ^ rsw));
                acc = __builtin_amdgcn_mfma_f32_16x16x32_bf16(afr, qf[ks], acc, 0, 0, 0);
            }
            f32x4 w;
#pragma unroll
            for (int jj = 0; jj < 4; ++jj)
                w[jj] = __expf(acc[jj] * SCALE) * lrow;
            *(f32x4*)(orow + s0 + ns * 16 + g * 4) = w;
        }
    }
}

// ---------------------------------------------------------------------------
extern "C" void kernel_launch(void* const* d_in, const int* in_sizes, int n_in,
                              void* d_out, int out_size, void* d_ws, size_t ws_size,
                              hipStream_t stream) {
    const float* x  = (const float*)d_in[0];
    const float* Wq = (const float*)d_in[1];
    const float* bq = (const float*)d_in[2];
    const float* Wk = (const float*)d_in[3];
    const float* bk = (const float*)d_in[4];
    const float* Wv = (const float*)d_in[5];
    const float* bv = (const float*)d_in[6];

    float* out_w   = (float*)d_out;            // [B,T,1] = 32768
    float* out_att = (float*)d_out + NB * NT;  // [B,T,T]

    char* ws = (char*)d_ws;
    bf16*  WT = (bf16*)ws;                       // 262144 B
    float* V  = (float*)(ws + 262144);           // 131072 B
    bf16*  QK = (bf16*)(ws + 393216);            // 16 MB
    float* pl = (float*)(ws + 17170432);         // NCH1*32768*4 = 1 MB
    float* pw = (float*)(ws + 18219008);         // 1 MB

    prep_wt<<<dim3(256), dim3(256), 0, stream>>>(Wq, Wk, WT);
    norm_proj<<<dim3((NB * NT) / 16), dim3(256), 0, stream>>>(x, Wv, bv, WT, bq, bk, QK, V);
    attn_pass1<<<dim3(NCH1, NB, NT / 64), dim3(256), 0, stream>>>(QK, V, pl, pw);
    attn_pass2<<<dim3(NCH2, NB, NT / 64), dim3(256), 0, stream>>>(QK, pl, pw, out_w, out_att);
}

// Round 8
// 182.657 us; speedup vs baseline: 1.1378x; 1.0205x over previous
//
#include <hip/hip_runtime.h>

// Problem constants (B=16, T=2048, D=512, A=128)
#define NB 16
#define NT 2048
#define ND 512
#define NA 128
#define EPSV 1e-6f
#define SCALE 0.08838834764831845f  // 128^-0.5
#define NCH 4        // s-chunks in attention
#define SCH 512      // s-chunk length

typedef __bf16 bf16;
typedef __bf16 bf16x4 __attribute__((ext_vector_type(4)));
typedef __bf16 bf16x8 __attribute__((ext_vector_type(8)));
typedef float f32x4 __attribute__((ext_vector_type(4)));

// ---------------------------------------------------------------------------
// Kernel 0: build W^T bf16 [256][512]  (rows 0..127 = Wq cols, 128..255 = Wk)
// ---------------------------------------------------------------------------
__global__ void prep_wt(const float* __restrict__ Wq, const float* __restrict__ Wk,
                        bf16* __restrict__ WT) {
    int n = blockIdx.x;
    const float* W = (n < NA) ? Wq : Wk;
    int col = n & (NA - 1);
    for (int k = threadIdx.x; k < ND; k += blockDim.x)
        WT[(size_t)n * ND + k] = (bf16)W[(size_t)k * NA + col];
}

// ---------------------------------------------------------------------------
// Kernel 1: fused norm + V + QK projection GEMM. 16 rows/block, grid 2048.
// ---------------------------------------------------------------------------
__launch_bounds__(256)
__global__ void norm_proj(const float* __restrict__ x, const float* __restrict__ Wv,
                          const float* __restrict__ bvp, const bf16* __restrict__ WT,
                          const float* __restrict__ bq, const float* __restrict__ bk,
                          bf16* __restrict__ QK, float* __restrict__ Vout) {
    __shared__ bf16 xn[16 * ND];  // 16 KB, XOR-swizzled rows
    const int tid = threadIdx.x;
    const int lane = tid & 63, wv = tid >> 6;
    const int row0 = blockIdx.x * 16;

    float wvv[8];
    float sumw = 0.f;
#pragma unroll
    for (int i = 0; i < 4; ++i) { wvv[i]     = Wv[lane * 4 + i];       sumw += wvv[i]; }
#pragma unroll
    for (int i = 0; i < 4; ++i) { wvv[4 + i] = Wv[256 + lane * 4 + i]; sumw += wvv[4 + i]; }
#pragma unroll
    for (int m = 1; m < 64; m <<= 1) sumw += __shfl_xor(sumw, m);
    const float bvs = bvp[0];

#pragma unroll
    for (int r = 0; r < 4; ++r) {
        const int lrow = wv * 4 + r;
        const int grow = row0 + lrow;
        const float* xr = x + (size_t)grow * ND;
        f32x4 a = *(const f32x4*)(xr + lane * 4);
        f32x4 b = *(const f32x4*)(xr + 256 + lane * 4);
        float s = 0.f, sq = 0.f, dw = 0.f;
#pragma unroll
        for (int i = 0; i < 4; ++i) { s += a[i]; sq += a[i] * a[i]; dw += a[i] * wvv[i]; }
#pragma unroll
        for (int i = 0; i < 4; ++i) { s += b[i]; sq += b[i] * b[i]; dw += b[i] * wvv[4 + i]; }
#pragma unroll
        for (int m = 1; m < 64; m <<= 1) {
            s  += __shfl_xor(s, m);
            sq += __shfl_xor(sq, m);
            dw += __shfl_xor(dw, m);
        }
        const float mu  = s * (1.f / 512.f);
        float var = (sq - 512.f * mu * mu) * (1.f / 511.f);
        var = fmaxf(var, 0.f);
        const float inv = 1.f / (sqrtf(var) + EPSV);
        if (lane == 0) Vout[grow] = (dw - mu * sumw) * inv + bvs;

        const int sw = (lrow & 7) << 4;
        bf16x4 v0, v1;
#pragma unroll
        for (int i = 0; i < 4; ++i) v0[i] = (bf16)((a[i] - mu) * inv);
#pragma unroll
        for (int i = 0; i < 4; ++i) v1[i] = (bf16)((b[i] - mu) * inv);
        *(bf16x4*)((char*)xn + lrow * 1024 + ((lane * 8) ^ sw))       = v0;
        *(bf16x4*)((char*)xn + lrow * 1024 + ((512 + lane * 8) ^ sw)) = v1;
    }
    __syncthreads();

    const int c = lane & 15, g = lane >> 4;
    const int asw = (c & 7) << 4;
    f32x4 acc[4];
#pragma unroll
    for (int i = 0; i < 4; ++i) acc[i] = f32x4{0.f, 0.f, 0.f, 0.f};

    for (int ks = 0; ks < 16; ++ks) {
        const bf16x8 af = *(const bf16x8*)((const char*)xn + c * 1024 +
                                           ((ks * 64 + g * 16) ^ asw));
#pragma unroll
        for (int i = 0; i < 4; ++i) {
            const int n = wv * 64 + i * 16 + c;
            const bf16x8 bfr = *(const bf16x8*)(WT + (size_t)n * ND + ks * 32 + g * 8);
            acc[i] = __builtin_amdgcn_mfma_f32_16x16x32_bf16(af, bfr, acc[i], 0, 0, 0);
        }
    }
#pragma unroll
    for (int i = 0; i < 4; ++i) {
        const int n = wv * 64 + i * 16 + c;
        const float bias = (n < NA) ? bq[n] : bk[n - NA];
#pragma unroll
        for (int j = 0; j < 4; ++j)
            QK[(size_t)(row0 + g * 4 + j) * 256 + n] = (bf16)(acc[i][j] + bias);
    }
}

// ---------------------------------------------------------------------------
// Kernel 2: pass1 — per-chunk sums l = sum(exp s), w = sum(exp s * V).
// R4 structure exactly (measured best).
// ---------------------------------------------------------------------------
__launch_bounds__(256)
__global__ void attn_pass1(const bf16* __restrict__ QK, const float* __restrict__ Vg,
                           float* __restrict__ pl, float* __restrict__ pw) {
    __shared__ bf16 Kt[64 * NA];  // 16 KB, XOR-swizzled
    const int tid = threadIdx.x;
    const int lane = tid & 63, wv = tid >> 6;
    const int b = blockIdx.z, t0 = blockIdx.x * 64, sc = blockIdx.y;
    const int c = lane & 15, g = lane >> 4;
    const int trow = t0 + wv * 16 + c;

    bf16x8 qf[4];
    const bf16* qrow = QK + (size_t)(b * NT + trow) * 256;
#pragma unroll
    for (int ks = 0; ks < 4; ++ks) qf[ks] = *(const bf16x8*)(qrow + ks * 32 + g * 8);

    const int srow = tid >> 4, scc = tid & 15;
    const bf16* kbase = QK + (size_t)(b * NT + sc * SCH + srow) * 256 + NA + scc * 8;
    bf16* kdst = (bf16*)((char*)Kt + srow * 256 + ((scc * 16) ^ ((srow & 7) << 4)));
    bf16x8 sreg[4];

#pragma unroll
    for (int i = 0; i < 4; ++i)
        sreg[i] = *(const bf16x8*)(kbase + (size_t)(i * 16) * 256);

    const float* vbase = Vg + b * NT + sc * SCH;
    float l_loc = 0.f, w_loc = 0.f;

    for (int tt = 0; tt < SCH / 64; ++tt) {
        __syncthreads();
#pragma unroll
        for (int i = 0; i < 4; ++i)
            *(bf16x8*)((char*)kdst + i * 16 * 256) = sreg[i];
        if (tt + 1 < SCH / 64) {
#pragma unroll
            for (int i = 0; i < 4; ++i)
                sreg[i] = *(const bf16x8*)(kbase + (size_t)((tt + 1) * 64 + i * 16) * 256);
        }
        __syncthreads();

#pragma unroll
        for (int ns = 0; ns < 4; ++ns) {
            f32x4 acc = f32x4{0.f, 0.f, 0.f, 0.f};
            const int rr = ns * 16 + c;
            const int rsw = (rr & 7) << 4;
#pragma unroll
            for (int ks = 0; ks < 4; ++ks) {
                const bf16x8 afr = *(const bf16x8*)((const char*)Kt + rr * 256 +
                                                    ((ks * 64 + g * 16) ^ rsw));
                acc = __builtin_amdgcn_mfma_f32_16x16x32_bf16(afr, qf[ks], acc, 0, 0, 0);
            }
            const f32x4 vv = *(const f32x4*)(vbase + tt * 64 + ns * 16 + g * 4);
#pragma unroll
            for (int jj = 0; jj < 4; ++jj) {
                const float p = __expf(acc[jj] * SCALE);
                l_loc += p;
                w_loc += p * vv[jj];
            }
        }
    }

#pragma unroll
    for (int mask = 16; mask <= 32; mask <<= 1) {
        l_loc += __shfl_xor(l_loc, mask);
        w_loc += __shfl_xor(w_loc, mask);
    }
    if (g == 0) {
        const int idx = sc * (NB * NT) + b * NT + trow;
        pl[idx] = l_loc;
        pw[idx] = w_loc;
    }
}

// ---------------------------------------------------------------------------
// Kernel 3: merge the 4 chunk-partials -> 1/l, out_w
// ---------------------------------------------------------------------------
__global__ void attn_reduce(const float* __restrict__ pl, const float* __restrict__ pw,
                            float* __restrict__ linv, float* __restrict__ out_w) {
    const int r = blockIdx.x * 256 + threadIdx.x;  // 0 .. NB*NT-1
    float L = 0.f, W = 0.f;
#pragma unroll
    for (int ch = 0; ch < NCH; ++ch) {
        L += pl[ch * (NB * NT) + r];
        W += pw[ch * (NB * NT) + r];
    }
    linv[r] = 1.f / L;
    out_w[r] = W / L;
}

// ---------------------------------------------------------------------------
// Kernel 4: pass2 — recompute scores, write normalized w_att.
// 128 t-rows per block (K staging amortized 2x). Grid 16x4x16 = 1024 blocks,
// fully resident (4 blocks/CU).
// ---------------------------------------------------------------------------
__launch_bounds__(256)
__global__ void attn_pass2(const bf16* __restrict__ QK, const float* __restrict__ linv,
                           float* __restrict__ out_att) {
    __shared__ bf16 Kt[64 * NA];
    const int tid = threadIdx.x;
    const int lane = tid & 63, wv = tid >> 6;
    const int b = blockIdx.z, t0 = blockIdx.x * 128, sc = blockIdx.y;
    const int c = lane & 15, g = lane >> 4;
    const int trowA = t0 + wv * 16 + c;       // first 64-row half
    const int trowB = trowA + 64;             // second half

    bf16x8 qfA[4], qfB[4];
    const bf16* qrowA = QK + (size_t)(b * NT + trowA) * 256;
    const bf16* qrowB = QK + (size_t)(b * NT + trowB) * 256;
#pragma unroll
    for (int ks = 0; ks < 4; ++ks) {
        qfA[ks] = *(const bf16x8*)(qrowA + ks * 32 + g * 8);
        qfB[ks] = *(const bf16x8*)(qrowB + ks * 32 + g * 8);
    }
    const float liA = linv[b * NT + trowA];
    const float liB = linv[b * NT + trowB];

    const int srow = tid >> 4, scc = tid & 15;
    const bf16* kbase = QK + (size_t)(b * NT + sc * SCH + srow) * 256 + NA + scc * 8;
    bf16* kdst = (bf16*)((char*)Kt + srow * 256 + ((scc * 16) ^ ((srow & 7) << 4)));
    bf16x8 sreg[4];

#pragma unroll
    for (int i = 0; i < 4; ++i)
        sreg[i] = *(const bf16x8*)(kbase + (size_t)(i * 16) * 256);

    float* orowA = out_att + (size_t)(b * NT + trowA) * NT;
    float* orowB = out_att + (size_t)(b * NT + trowB) * NT;

    for (int tt = 0; tt < SCH / 64; ++tt) {
        __syncthreads();
#pragma unroll
        for (int i = 0; i < 4; ++i)
            *(bf16x8*)((char*)kdst + i * 16 * 256) = sreg[i];
        if (tt + 1 < SCH / 64) {
#pragma unroll
            for (int i = 0; i < 4; ++i)
                sreg[i] = *(const bf16x8*)(kbase + (size_t)((tt + 1) * 64 + i * 16) * 256);
        }
        __syncthreads();

        const int s0 = sc * SCH + tt * 64;
#pragma unroll
        for (int ns = 0; ns < 4; ++ns) {
            const int rr = ns * 16 + c;
            const int rsw = (rr & 7) << 4;
            bf16x8 af[4];
#pragma unroll
            for (int ks = 0; ks < 4; ++ks)
                af[ks] = *(const bf16x8*)((const char*)Kt + rr * 256 +
                                          ((ks * 64 + g * 16) ^ rsw));
            f32x4 accA = f32x4{0.f, 0.f, 0.f, 0.f};
            f32x4 accB = f32x4{0.f, 0.f, 0.f, 0.f};
#pragma unroll
            for (int ks = 0; ks < 4; ++ks) {
                accA = __builtin_amdgcn_mfma_f32_16x16x32_bf16(af[ks], qfA[ks], accA, 0, 0, 0);
                accB = __builtin_amdgcn_mfma_f32_16x16x32_bf16(af[ks], qfB[ks], accB, 0, 0, 0);
            }
            f32x4 wA, wB;
#pragma unroll
            for (int jj = 0; jj < 4; ++jj) {
                wA[jj] = __expf(accA[jj] * SCALE) * liA;
                wB[jj] = __expf(accB[jj] * SCALE) * liB;
            }
            *(f32x4*)(orowA + s0 + ns * 16 + g * 4) = wA;
            *(f32x4*)(orowB + s0 + ns * 16 + g * 4) = wB;
        }
    }
}

// ---------------------------------------------------------------------------
extern "C" void kernel_launch(void* const* d_in, const int* in_sizes, int n_in,
                              void* d_out, int out_size, void* d_ws, size_t ws_size,
                              hipStream_t stream) {
    const float* x  = (const float*)d_in[0];
    const float* Wq = (const float*)d_in[1];
    const float* bq = (const float*)d_in[2];
    const float* Wk = (const float*)d_in[3];
    const float* bk = (const float*)d_in[4];
    const float* Wv = (const float*)d_in[5];
    const float* bv = (const float*)d_in[6];

    float* out_w   = (float*)d_out;            // [B,T,1] = 32768
    float* out_att = (float*)d_out + NB * NT;  // [B,T,T]

    char* ws = (char*)d_ws;
    bf16*  WT   = (bf16*)ws;                         // 262144 B
    float* V    = (float*)(ws + 262144);             // 131072 B
    bf16*  QK   = (bf16*)(ws + 393216);              // 16 MB
    float* pl   = (float*)(ws + 17170432);           // 512 KB
    float* pw   = (float*)(ws + 17694720);           // 512 KB
    float* linv = (float*)(ws + 18219008);           // 128 KB

    prep_wt<<<dim3(256), dim3(256), 0, stream>>>(Wq, Wk, WT);
    norm_proj<<<dim3((NB * NT) / 16), dim3(256), 0, stream>>>(x, Wv, bv, WT, bq, bk, QK, V);
    attn_pass1<<<dim3(NT / 64, NCH, NB), dim3(256), 0, stream>>>(QK, V, pl, pw);
    attn_reduce<<<dim3((NB * NT) / 256), dim3(256), 0, stream>>>(pl, pw, linv, out_w);
    attn_pass2<<<dim3(NT / 128, NCH, NB), dim3(256), 0, stream>>>(QK, linv, out_att);
}